// Round 10
// baseline (34.979 us; speedup 1.0000x reference)
//
#include <hip/hip_runtime.h>
#include <math.h>

#define TOPM 2048   // top-M node ids served by the dense GEMM table

typedef _Float16 f16x8 __attribute__((ext_vector_type(8)));
typedef _Float16 f16x4 __attribute__((ext_vector_type(4)));
typedef float    f32x4 __attribute__((ext_vector_type(4)));

// ---- DPP wave reductions: VALU pipe only ----
template<int CTRL, int ROW_MASK>
__device__ __forceinline__ float dpp_add(float v) {
    const int s = __builtin_amdgcn_update_dpp(0, __float_as_int(v), CTRL, ROW_MASK, 0xf, false);
    return v + __int_as_float(s);
}
template<int CTRL, int ROW_MASK>
__device__ __forceinline__ float dpp_mul(float v) {
    const int s = __builtin_amdgcn_update_dpp(0x3f800000, __float_as_int(v), CTRL, ROW_MASK, 0xf, false);
    return v * __int_as_float(s);
}
__device__ __forceinline__ float wave_sum63(float v) {   // total in lane 63
    v = dpp_add<0x111, 0xf>(v); v = dpp_add<0x112, 0xf>(v); v = dpp_add<0x114, 0xf>(v);
    v = dpp_add<0x118, 0xf>(v); v = dpp_add<0x142, 0xa>(v); v = dpp_add<0x143, 0xc>(v);
    return v;
}
__device__ __forceinline__ float wave_prod63(float v) {  // product in lane 63
    v = dpp_mul<0x111, 0xf>(v); v = dpp_mul<0x112, 0xf>(v); v = dpp_mul<0x114, 0xf>(v);
    v = dpp_mul<0x118, 0xf>(v); v = dpp_mul<0x142, 0xa>(v); v = dpp_mul<0x143, 0xc>(v);
    return v;
}
__device__ __forceinline__ float readlane_f(float v, int l) {
    return __int_as_float(__builtin_amdgcn_readlane(__float_as_int(v), l));
}
__device__ __forceinline__ float dot8(float4 a, float4 b, float4 c, float4 d) {
    return a.x*b.x + a.y*b.y + a.z*b.z + a.w*b.w + c.x*d.x + c.y*d.y + c.z*d.z + c.w*d.w;
}
__device__ __forceinline__ void gld16(const void* g, void* l) {
    __builtin_amdgcn_global_load_lds((const __attribute__((address_space(1))) void*)g,
                                     (__attribute__((address_space(3))) void*)l, 16, 0, 0);
}

// K0: convert W-top (TOPM x 512) and x (B x 512) fp32 -> fp16 into workspace.
__global__ __launch_bounds__(256)
void conv_f16(const float* __restrict__ wsrc, const float* __restrict__ xsrc,
              _Float16* __restrict__ Wh, _Float16* __restrict__ xh,
              int n0, int ntot)
{
    const int i = blockIdx.x * 256 + threadIdx.x;
    if (i >= ntot) return;
    const float4 v = (i < n0) ? reinterpret_cast<const float4*>(wsrc)[i]
                              : reinterpret_cast<const float4*>(xsrc)[i - n0];
    f16x4 h; h[0] = (_Float16)v.x; h[1] = (_Float16)v.y; h[2] = (_Float16)v.z; h[3] = (_Float16)v.w;
    if (i < n0) reinterpret_cast<f16x4*>(Wh)[i] = h;
    else        reinterpret_cast<f16x4*>(xh)[i - n0] = h;
}

// K1: Y[m][n] = sum_k Wh[m][k] * xh[n][k]. BM=128, BN=64, BK=64.
// Staging uses r8's PROVEN pattern: wave-uniform LDS dest ((i*256+w*64)*16,
// HW writes lane l at dest+l*16 [m104/m108]) + per-lane pre-swizzled global
// source col ((f&7)^(row&7))*8 -> LDS slot (f&7) holds global chunk
// (f&7)^(row&7); read at slot kc^(row&7) recovers global chunk kc.
// New vs r8: double-buffered LDS + counted vmcnt(6) (tile t+1's 6 loads stay
// in flight across the barrier; no vmcnt(0) drain in the main loop).
__global__ __launch_bounds__(256)
void top_gemm(const _Float16* __restrict__ Wh, const _Float16* __restrict__ xh,
              float* __restrict__ Y, int B)
{
    __shared__ __align__(16) _Float16 At[2][128 * 64];  // 2 x 16 KB
    __shared__ __align__(16) _Float16 Bt[2][64 * 64];   // 2 x 8 KB

    const int tid  = threadIdx.x;
    const int lane = tid & 63;
    const int w    = tid >> 6;
    const int bm   = (blockIdx.x & (TOPM / 128 - 1)) * 128;
    const int bn   = (blockIdx.x / (TOPM / 128)) * 64;
    const int wr   = w & 1;      // wave computes 64x32 at (wr*64, wc*32)
    const int wc   = w >> 1;
    const int l15  = lane & 15;
    const int g    = lane >> 4;

    f32x4 acc[4][2] = {};

    // 6 gld16 per thread per k-tile (4 A + 2 B), wave-uniform dests.
    #define STAGE(buf, k0)                                                        \
        {                                                                         \
            _Float16* a_ = At[buf]; _Float16* b_ = Bt[buf];                       \
            _Pragma("unroll")                                                     \
            for (int i_ = 0; i_ < 4; ++i_) {   /* A tile: 128x64 f16 */           \
                const int f_ = i_ * 256 + tid;                                    \
                const int row_ = f_ >> 3;                                         \
                const int sc_ = ((f_ & 7) ^ (row_ & 7)) * 8;                      \
                gld16(Wh + (size_t)(bm + row_) * 512 + (k0) + sc_,                \
                      (char*)a_ + (i_ * 256 + w * 64) * 16);                      \
            }                                                                     \
            _Pragma("unroll")                                                     \
            for (int i_ = 0; i_ < 2; ++i_) {   /* B tile: 64x64 f16 */            \
                const int f_ = i_ * 256 + tid;                                    \
                const int row_ = f_ >> 3;                                         \
                const int sc_ = ((f_ & 7) ^ (row_ & 7)) * 8;                      \
                gld16(xh + (size_t)(bn + row_) * 512 + (k0) + sc_,                \
                      (char*)b_ + (i_ * 256 + w * 64) * 16);                      \
            }                                                                     \
        }

    STAGE(0, 0);
    for (int t = 0; t < 8; ++t) {
        if (t < 7) {
            STAGE((t + 1) & 1, (t + 1) * 64);
            asm volatile("s_waitcnt vmcnt(6)" ::: "memory");  // tile t landed; t+1 in flight
        } else {
            asm volatile("s_waitcnt vmcnt(0)" ::: "memory");
        }
        __builtin_amdgcn_s_barrier();
        asm volatile("" ::: "memory");

        const _Float16* a_ = At[t & 1];
        const _Float16* b_ = Bt[t & 1];
        #pragma unroll
        for (int kk = 0; kk < 2; ++kk) {
            f16x8 af[4], bf[2];
            #pragma unroll
            for (int mi = 0; mi < 4; ++mi) {
                const int row = wr * 64 + mi * 16 + l15;
                const int cb = ((kk * 4 + g) ^ (row & 7)) * 16;
                af[mi] = *reinterpret_cast<const f16x8*>((const char*)a_ + row * 128 + cb);
            }
            #pragma unroll
            for (int ni = 0; ni < 2; ++ni) {
                const int row = wc * 32 + ni * 16 + l15;
                const int cb = ((kk * 4 + g) ^ (row & 7)) * 16;
                bf[ni] = *reinterpret_cast<const f16x8*>((const char*)b_ + row * 128 + cb);
            }
            #pragma unroll
            for (int mi = 0; mi < 4; ++mi)
                #pragma unroll
                for (int ni = 0; ni < 2; ++ni)
                    acc[mi][ni] = __builtin_amdgcn_mfma_f32_16x16x32_f16(af[mi], bf[ni], acc[mi][ni], 0, 0, 0);
        }
        asm volatile("" ::: "memory");
        __builtin_amdgcn_s_barrier();   // all reads of buf[t&1] done before restage
    }
    #undef STAGE

    #pragma unroll
    for (int mi = 0; mi < 4; ++mi)
        #pragma unroll
        for (int ni = 0; ni < 2; ++ni)
            #pragma unroll
            for (int r = 0; r < 4; ++r) {
                const int m = bm + wr * 64 + mi * 16 + g * 4 + r;
                const int n = bn + wc * 32 + ni * 16 + l15;
                Y[(size_t)m * B + n] = acc[mi][ni][r];
            }
}

// K2: wave per (b,r) pair. Entries with node id >= tb from table Y (bias added
// here); the rest gathered via compact ballot-driven batch (any distribution).
__global__ __launch_bounds__(256)
void huff_combine(const float* __restrict__ x, const int* __restrict__ tgt,
                  const float* __restrict__ W, const float* __restrict__ bias,
                  const int* __restrict__ paths, const float* __restrict__ codes,
                  const float* __restrict__ Y, float* __restrict__ out,
                  int R, int N, int B)
{
    const int lane = threadIdx.x & 63;
    const int p = blockIdx.x * 4 + (threadIdx.x >> 6);
    const int b = p / R;
    const int tb = N - TOPM;

    const float4* xr = reinterpret_cast<const float4*>(x + (size_t)b * 512);
    const float4 xa = xr[lane], xb = xr[lane + 64];

    const int c  = tgt[p];
    const int dd = (lane < 16) ? lane : 15;
    const int   nd = paths[(size_t)c * 16 + dd];
    const float cd = codes[(size_t)c * 16 + dd];
    const float sd = 1.0f - 2.0f * cd;
    const float bv = bias[nd];

    // table-served factors
    float f = 1.0f;
    if (lane < 16 && nd >= tb)
        f = 1.0f + __expf(-sd * (Y[(size_t)(nd - tb) * B + b] + bv));
    f = wave_prod63(f);
    float q = readlane_f(f, 63);

    // gather-needed entries (wave-uniform mask)
    unsigned mm = (unsigned)(__ballot(lane < 16 && nd < tb) & 0xFFFFull);
    int dl[6];
    #pragma unroll
    for (int s = 0; s < 6; ++s) {
        dl[s] = mm ? (int)__builtin_ctz(mm) : -1;
        if (mm) mm &= mm - 1;
    }

    float4 wA[6], wB[6];
    #pragma unroll
    for (int s = 0; s < 6; ++s)
        if (dl[s] >= 0) {
            const int nid = __builtin_amdgcn_readlane(nd, dl[s]);
            const float4* wr = reinterpret_cast<const float4*>(W + (size_t)nid * 512);
            wA[s] = wr[lane]; wB[s] = wr[lane + 64];
        }
    float a6[6];
    #pragma unroll
    for (int s = 0; s < 6; ++s)
        a6[s] = (dl[s] >= 0) ? dot8(xa, wA[s], xb, wB[s]) : 0.0f;
    #pragma unroll
    for (int s = 0; s < 6; ++s)
        if (dl[s] >= 0) a6[s] = wave_sum63(a6[s]);
    #pragma unroll
    for (int s = 0; s < 6; ++s)
        if (dl[s] >= 0) {
            const float tot = readlane_f(a6[s], 63) + readlane_f(bv, dl[s]);
            q *= 1.0f + __expf(-readlane_f(sd, dl[s]) * tot);
        }

    // remainder (rare: >6 gathered entries per path)
    while (mm) {
        const int d = (int)__builtin_ctz(mm); mm &= mm - 1;
        const int nid = __builtin_amdgcn_readlane(nd, d);
        const float4* wr = reinterpret_cast<const float4*>(W + (size_t)nid * 512);
        float a = dot8(xa, wr[lane], xb, wr[lane + 64]);
        a = wave_sum63(a);
        q *= 1.0f + __expf(-readlane_f(sd, d) * (readlane_f(a, 63) + readlane_f(bv, d)));
    }

    if (lane == 0) out[p] = 1.0f / q;
}

// Generic fallback for unexpected shapes.
__global__ __launch_bounds__(256)
void huff_kernel_gen(const float* __restrict__ x, const int* __restrict__ tgt,
                     const float* __restrict__ W, const float* __restrict__ bias,
                     const int* __restrict__ paths, const float* __restrict__ codes,
                     float* __restrict__ out, int R, int I, int D, int npairs)
{
    const int lane = threadIdx.x & 63;
    const int p = blockIdx.x * 4 + (threadIdx.x >> 6);
    if (p >= npairs) return;
    const int b = p / R;
    const float4* xrow = reinterpret_cast<const float4*>(x + (size_t)b * I);
    const float4 xa = xrow[lane];
    const float4 xb = xrow[lane + 64];
    const int c = tgt[p];
    float q = 1.0f;
    for (int d = 0; d < D; ++d) {
        const int node = paths[(size_t)c * D + d];
        const float4* wr = reinterpret_cast<const float4*>(W + (size_t)node * I);
        float acc = dot8(xa, wr[lane], xb, wr[lane + 64]);
        #pragma unroll
        for (int off = 32; off; off >>= 1) acc += __shfl_xor(acc, off, 64);
        const float t = acc + bias[node];
        const float s = 1.0f - 2.0f * codes[(size_t)c * D + d];
        q *= 1.0f + __expf(-s * t);
    }
    if (lane == 0) out[p] = 1.0f / q;
}

extern "C" void kernel_launch(void* const* d_in, const int* in_sizes, int n_in,
                              void* d_out, int out_size, void* d_ws, size_t ws_size,
                              hipStream_t stream) {
    const float* x     = (const float*)d_in[0];
    const int*   tgt   = (const int*)  d_in[1];
    const float* W     = (const float*)d_in[2];
    const float* bias  = (const float*)d_in[3];
    const int*   paths = (const int*)  d_in[4];
    const float* codes = (const float*)d_in[5];
    float* out = (float*)d_out;

    const int N = in_sizes[3];            // total_nodes = nb_classes - 1
    const int C = N + 1;                  // nb_classes
    const int I = in_sizes[2] / N;        // input dim (512)
    const int B = in_sizes[0] / I;        // batch (1024)
    const int R = in_sizes[1] / B;        // requests (8)
    const int D = in_sizes[4] / C;        // max path depth

    const int npairs = B * R;

    const size_t y_bytes  = (size_t)TOPM * B * sizeof(float);
    const size_t wh_bytes = (size_t)TOPM * 512 * sizeof(_Float16);
    const size_t xh_bytes = (size_t)B * 512 * sizeof(_Float16);
    const size_t ws_need  = y_bytes + wh_bytes + xh_bytes;

    if (D == 16 && I == 512 && (B % 64) == 0 && (npairs % 4) == 0 &&
        N > TOPM + 64 && ws_size >= ws_need) {
        float*     Y  = (float*)d_ws;
        _Float16*  Wh = (_Float16*)((char*)d_ws + y_bytes);
        _Float16*  xh = (_Float16*)((char*)d_ws + y_bytes + wh_bytes);
        const int tb = N - TOPM;

        const int n0   = TOPM * 512 / 4;
        const int ntot = n0 + B * 512 / 4;
        conv_f16<<<(ntot + 255) / 256, 256, 0, stream>>>(W + (size_t)tb * 512, x, Wh, xh, n0, ntot);
        top_gemm<<<(TOPM / 128) * (B / 64), 256, 0, stream>>>(Wh, xh, Y, B);
        huff_combine<<<npairs / 4, 256, 0, stream>>>(x, tgt, W, bias, paths, codes,
                                                     Y, out, R, N, B);
    } else {
        const int grid = (npairs + 3) / 4;
        huff_kernel_gen<<<grid, 256, 0, stream>>>(x, tgt, W, bias, paths, codes,
                                                  out, R, I, D, npairs);
    }
}

// Round 11
// 24.143 us; speedup vs baseline: 1.4488x; 1.4488x over previous
//
#include <hip/hip_runtime.h>
#include <math.h>

#define HOTROWS 2048   // top ids kept L2-resident (4 MB = one XCD L2)

typedef float fvec4 __attribute__((ext_vector_type(4)));

// ---- DPP wave reduction: VALU pipe only, no LDS/DS instructions ----
template<int CTRL, int ROW_MASK>
__device__ __forceinline__ float dpp_add(float v) {
    const int s = __builtin_amdgcn_update_dpp(0, __float_as_int(v),
                                              CTRL, ROW_MASK, 0xf, false);
    return v + __int_as_float(s);
}
// Full 64-lane sum; total lands in lane 63.
__device__ __forceinline__ float wave_sum63(float v) {
    v = dpp_add<0x111, 0xf>(v);  // row_shr:1
    v = dpp_add<0x112, 0xf>(v);  // row_shr:2
    v = dpp_add<0x114, 0xf>(v);  // row_shr:4
    v = dpp_add<0x118, 0xf>(v);  // row_shr:8
    v = dpp_add<0x142, 0xa>(v);  // row_bcast:15
    v = dpp_add<0x143, 0xc>(v);  // row_bcast:31 -> lane 63 = total
    return v;
}
__device__ __forceinline__ float readlane_f(float v, int l) {
    return __int_as_float(__builtin_amdgcn_readlane(__float_as_int(v), l));
}
__device__ __forceinline__ float dot8v(fvec4 a, fvec4 b, fvec4 c, fvec4 d) {
    return a[0]*b[0] + a[1]*b[1] + a[2]*b[2] + a[3]*b[3]
         + c[0]*d[0] + c[1]*d[1] + c[2]*d[2] + c[3]*d[3];
}

// Fast path (D==16, I==512, npairs even): TWO waves per (b,r) pair.
// Wave half h handles depths 8h..8h+7. Hot rows (id >= tb, the re-read
// top-of-tree) use normal cached loads; deep rows (id < tb, ~unique per
// pair) use NON-TEMPORAL loads so their stream does not evict the 4MB of
// hot rows from each XCD's L2 (anti-thrash).
__global__ __launch_bounds__(256, 4)
void huff_half(const float* __restrict__ x, const int* __restrict__ tgt,
               const float* __restrict__ W, const float* __restrict__ bias,
               const int* __restrict__ paths, const float* __restrict__ codes,
               float* __restrict__ out, int R, int I, int tb)
{
    __shared__ float qsh[2][2];
    const int lane = threadIdx.x & 63;
    const int w    = threadIdx.x >> 6;   // 0..3
    const int pi   = w >> 1;             // pair slot within block
    const int h    = w & 1;              // depth half
    const int p    = blockIdx.x * 2 + pi;
    const int b    = p / R;

    // x row: I == 512 -> two fully-coalesced 1KB wave loads (hot, cached)
    const fvec4* xrow = reinterpret_cast<const fvec4*>(x + (size_t)b * I);
    const fvec4 xa = xrow[lane];
    const fvec4 xb = xrow[lane + 64];

    const int c     = tgt[p];
    const int dglob = h * 8 + (lane & 7);            // this wave's 8 depths
    const int   nd = paths[(size_t)c * 16 + dglob];
    const float cd = codes[(size_t)c * 16 + dglob];
    const float sd = 1.0f - 2.0f * cd;               // sign
    const float bv = bias[nd];

    float acc[8];
    #pragma unroll
    for (int d = 0; d < 8; ++d) {
        const int nid = __builtin_amdgcn_readlane(nd, d);   // uniform node id
        const fvec4* wr = reinterpret_cast<const fvec4*>(W + (size_t)nid * I);
        fvec4 wa, wb;
        if (nid >= tb) {                 // hot top-of-tree row: keep in L2
            wa = wr[lane]; wb = wr[lane + 64];
        } else {                         // deep row: streaming, don't thrash L2
            wa = __builtin_nontemporal_load(&wr[lane]);
            wb = __builtin_nontemporal_load(&wr[lane + 64]);
        }
        acc[d] = dot8v(xa, wa, xb, wb);
    }

    // 8 interleaved 6-step DPP chains (VALU pipe)
    #pragma unroll
    for (int d = 0; d < 8; ++d) acc[d] = wave_sum63(acc[d]);

    // partial q over this wave's 8 depths: prod sigmoid = 1/prod(1+exp(-s*t))
    float q = 1.0f;
    #pragma unroll
    for (int d = 0; d < 8; ++d) {
        const float tot = readlane_f(acc[d], 63);
        const float bb  = readlane_f(bv, d);
        const float ss  = readlane_f(sd, d);
        q *= 1.0f + __expf(-ss * (tot + bb));
    }
    if (lane == 0) qsh[pi][h] = q;
    __syncthreads();
    if (h == 0 && lane == 0) out[p] = 1.0f / (qsh[pi][0] * qsh[pi][1]);
}

// Generic fallback for unexpected shapes (shfl-based, correctness path).
__global__ __launch_bounds__(256)
void huff_kernel_gen(const float* __restrict__ x, const int* __restrict__ tgt,
                     const float* __restrict__ W, const float* __restrict__ bias,
                     const int* __restrict__ paths, const float* __restrict__ codes,
                     float* __restrict__ out, int R, int I, int D, int npairs)
{
    const int lane = threadIdx.x & 63;
    const int p = blockIdx.x * 4 + (threadIdx.x >> 6);
    if (p >= npairs) return;
    const int b = p / R;
    const fvec4* xrow = reinterpret_cast<const fvec4*>(x + (size_t)b * I);
    const fvec4 xa = xrow[lane];
    const fvec4 xb = xrow[lane + 64];
    const int c = tgt[p];
    float q = 1.0f;
    for (int d = 0; d < D; ++d) {
        const int node = paths[(size_t)c * D + d];
        const fvec4* wr = reinterpret_cast<const fvec4*>(W + (size_t)node * I);
        float acc = dot8v(xa, wr[lane], xb, wr[lane + 64]);
        #pragma unroll
        for (int off = 32; off; off >>= 1) acc += __shfl_xor(acc, off, 64);
        const float t = acc + bias[node];
        const float s = 1.0f - 2.0f * codes[(size_t)c * D + d];
        q *= 1.0f + __expf(-s * t);
    }
    if (lane == 0) out[p] = 1.0f / q;
}

extern "C" void kernel_launch(void* const* d_in, const int* in_sizes, int n_in,
                              void* d_out, int out_size, void* d_ws, size_t ws_size,
                              hipStream_t stream) {
    const float* x     = (const float*)d_in[0];
    const int*   tgt   = (const int*)  d_in[1];
    const float* W     = (const float*)d_in[2];
    const float* bias  = (const float*)d_in[3];
    const int*   paths = (const int*)  d_in[4];
    const float* codes = (const float*)d_in[5];
    float* out = (float*)d_out;

    const int N = in_sizes[3];            // total_nodes = nb_classes - 1
    const int C = N + 1;                  // nb_classes
    const int I = in_sizes[2] / N;        // input dim (512)
    const int B = in_sizes[0] / I;        // batch (1024)
    const int R = in_sizes[1] / B;        // requests (8)
    const int D = in_sizes[4] / C;        // max path depth

    const int npairs = B * R;
    const int tb = N - HOTROWS;           // if N<=HOTROWS: tb<=0 -> all cached

    if (D == 16 && I == 512 && (npairs & 1) == 0) {
        // 2 waves per pair, 2 pairs per 256-thread block
        huff_half<<<npairs / 2, 256, 0, stream>>>(x, tgt, W, bias, paths, codes,
                                                  out, R, I, tb);
    } else {
        const int grid = (npairs + 3) / 4;
        huff_kernel_gen<<<grid, 256, 0, stream>>>(x, tgt, W, bias, paths, codes,
                                                  out, R, I, D, npairs);
    }
}